// Round 10
// baseline (228.242 us; speedup 1.0000x reference)
//
#include <hip/hip_runtime.h>
#include <math.h>

#define D_IN   256
#define D_E    64
#define N_SUP  16384
#define NQ     256
#define KSEL   32
#define RTOLC  1e-5f
#define ATOLC  1e-5f
#define INV_T  10.0f    // 1/TEMPERATURE

#define CHUNK  512      // support rows per phase-A block
#define NCH    32       // support chunks
#define QG     8        // queries per phase-A block (= waves)
#define NQG    32       // query groups

typedef unsigned long long ull;

__device__ __forceinline__ float gelu_exact(float x) {
    return 0.5f * x * (1.0f + erff(x * 0.70710678118654752440f));
}

// ---------------------------------------------------------------------------
// Prep: pack W transposed into float4-k-packed layout WP[k4*64+f] =
// {W[f][4k4..4k4+4)} so embed lanes (lane = f) load W coalesced 16B.
__global__ __launch_bounds__(256) void prep_w(
    const float* __restrict__ W1, const float* __restrict__ W2,
    const float* __restrict__ W3,
    float4* __restrict__ W1P, float4* __restrict__ W2P, float4* __restrict__ W3P)
{
    const int t = blockIdx.x * 256 + threadIdx.x;
    if (t < 64 * 64) {                   // W1P: k4 in [0,64)
        int k4 = t >> 6, f = t & 63;
        const float* w = W1 + (size_t)f * D_IN + 4 * k4;
        W1P[t] = make_float4(w[0], w[1], w[2], w[3]);
    }
    if (t < 16 * 64) {                   // W2P/W3P: k4 in [0,16)
        int k4 = t >> 6, f = t & 63;
        const float* w2 = W2 + (size_t)f * D_E + 4 * k4;
        W2P[t] = make_float4(w2[0], w2[1], w2[2], w2[3]);
        const float* w3 = W3 + (size_t)f * D_E + 4 * k4;
        W3P[t] = make_float4(w3[0], w3[1], w3[2], w3[3]);
    }
}

// ---------------------------------------------------------------------------
// Embed: 520 blocks x 256 threads (4 waves), 32 rows/block, wave = 8 rows,
// lane = feature f. W in per-lane VGPRs (coalesced float4 from W*P); x via
// wave-uniform s_load (scalar pipe); h exchanged through per-wave LDS rows
// (no barriers anywhere). FMA chain per (row,f) is k-ascending as always.
__global__ __launch_bounds__(256) void embed_kernel(
    const float* __restrict__ sx, const float* __restrict__ x,
    const float4* __restrict__ W1P, const float* __restrict__ b1,
    const float4* __restrict__ W2P, const float* __restrict__ b2,
    const float4* __restrict__ W3P, const float* __restrict__ b3,
    float* __restrict__ s_emb, float* __restrict__ s_norm,
    float* __restrict__ q_emb, float* __restrict__ q_norm)
{
    __shared__ float hl[32][68];     // [row][f] hidden exchange (8.7 KB)

    const int tid = threadIdx.x;
    const int f   = tid & 63;
    const int wv  = tid >> 6;
    const int r0  = __builtin_amdgcn_readfirstlane(wv * 8);
    const bool isq = blockIdx.x >= (N_SUP / 32);
    const int  rowbase = isq ? (int)(blockIdx.x - N_SUP / 32) * 32
                             : (int)blockIdx.x * 32;
    const float* src = (isq ? x : sx) + (size_t)rowbase * D_IN;

    // ---- layer 1: W1 chunked 4x, x via uniform s_load
    const float b1v = b1[f];
    float acc[8];
    #pragma unroll
    for (int r = 0; r < 8; ++r) acc[r] = b1v;

    #pragma unroll
    for (int kc = 0; kc < 4; ++kc) {
        float4 wreg[16];
        #pragma unroll
        for (int j = 0; j < 16; ++j)
            wreg[j] = W1P[(kc * 16 + j) * 64 + f];
        #pragma unroll
        for (int j = 0; j < 16; ++j) {
            #pragma unroll
            for (int r = 0; r < 8; ++r) {
                const float* xp = src + (size_t)(r0 + r) * D_IN + kc * 64 + j * 4;
                acc[r] = fmaf(wreg[j].x, xp[0], acc[r]);
                acc[r] = fmaf(wreg[j].y, xp[1], acc[r]);
                acc[r] = fmaf(wreg[j].z, xp[2], acc[r]);
                acc[r] = fmaf(wreg[j].w, xp[3], acc[r]);
            }
        }
    }
    #pragma unroll
    for (int r = 0; r < 8; ++r) hl[r0 + r][f] = gelu_exact(acc[r]);   // wave-local

    // ---- layer 2 (h from per-wave LDS broadcast, W2 in VGPRs)
    {
        float4 wreg[16];
        #pragma unroll
        for (int j = 0; j < 16; ++j) wreg[j] = W2P[j * 64 + f];
        const float b2v = b2[f];
        float a2[8];
        #pragma unroll
        for (int r = 0; r < 8; ++r) a2[r] = b2v;
        #pragma unroll
        for (int j = 0; j < 16; ++j) {
            #pragma unroll
            for (int r = 0; r < 8; ++r) {
                float4 hv = *reinterpret_cast<const float4*>(&hl[r0 + r][4 * j]);
                a2[r] = fmaf(wreg[j].x, hv.x, a2[r]);
                a2[r] = fmaf(wreg[j].y, hv.y, a2[r]);
                a2[r] = fmaf(wreg[j].z, hv.z, a2[r]);
                a2[r] = fmaf(wreg[j].w, hv.w, a2[r]);
            }
        }
        #pragma unroll
        for (int r = 0; r < 8; ++r) acc[r] = gelu_exact(a2[r]);
    }
    #pragma unroll
    for (int r = 0; r < 8; ++r) hl[r0 + r][f] = acc[r];     // hB, same wave

    // ---- layer 3 + sigmoid + norm
    {
        float4 wreg[16];
        #pragma unroll
        for (int j = 0; j < 16; ++j) wreg[j] = W3P[j * 64 + f];
        const float b3v = b3[f];
        float a3[8];
        #pragma unroll
        for (int r = 0; r < 8; ++r) a3[r] = b3v;
        #pragma unroll
        for (int j = 0; j < 16; ++j) {
            #pragma unroll
            for (int r = 0; r < 8; ++r) {
                float4 hv = *reinterpret_cast<const float4*>(&hl[r0 + r][4 * j]);
                a3[r] = fmaf(wreg[j].x, hv.x, a3[r]);
                a3[r] = fmaf(wreg[j].y, hv.y, a3[r]);
                a3[r] = fmaf(wreg[j].z, hv.z, a3[r]);
                a3[r] = fmaf(wreg[j].w, hv.w, a3[r]);
            }
        }
        float* E   = isq ? q_emb  : s_emb;
        float* Nrm = isq ? q_norm : s_norm;
        float nr[8];
        #pragma unroll
        for (int r = 0; r < 8; ++r) {
            float e = 1.0f / (1.0f + expf(-a3[r]));
            E[(size_t)(rowbase + r0 + r) * D_E + f] = e;    // coalesced dword
            nr[r] = e * e;
        }
        #pragma unroll
        for (int off = 1; off < 64; off <<= 1) {
            #pragma unroll
            for (int r = 0; r < 8; ++r) nr[r] += __shfl_xor(nr[r], off);
        }
        if (f == 0) {
            #pragma unroll
            for (int r = 0; r < 8; ++r) Nrm[rowbase + r0 + r] = nr[r];
        }
    }
}

// ---------------------------------------------------------------------------
// Phase A: grid 1024 = 4/CU (qg = b>>5, sc = b&31), 512 threads, wave=query.
// q via uniform s_load (SGPR fma operand); lane reads only its tile row from
// LDS (dbuf, 1 barrier/stage); d2 kept in registers (8/lane, static idx via
// full unroll). Selection: sort-8 + 32 rounds of u32-min + ballot (R9 scheme).
__global__ __launch_bounds__(512, 2) void knn_phaseA(
    const float* __restrict__ s_emb, const float* __restrict__ s_norm,
    const float* __restrict__ q_emb, const float* __restrict__ q_norm,
    const float* __restrict__ labels, ull* __restrict__ cand)
{
    __shared__ float tile[2][64 * 68];          // 34.8 KB
    __shared__ ull   win_l[QG][KSEL];           // 2 KB

    const int tid  = threadIdx.x;
    const int lane = tid & 63;
    const int wid  = tid >> 6;
    const int qg   = blockIdx.x >> 5;
    const int sc   = blockIdx.x & 31;
    const int qiu  = __builtin_amdgcn_readfirstlane(qg * QG + wid);
    const float* q0 = q_emb + (size_t)qiu * D_E;    // uniform -> s_load
    const float  qn = q_norm[qiu];

    #pragma unroll
    for (int i = 0; i < 2; ++i) {               // stage 0
        int g = i * 512 + tid;
        int row = g >> 4, c4 = g & 15;
        float4 v = *reinterpret_cast<const float4*>(
            s_emb + (size_t)(sc * CHUNK + row) * D_E + c4 * 4);
        *reinterpret_cast<float4*>(&tile[0][row * 68 + c4 * 4]) = v;
    }
    __syncthreads();

    float d2s[8];
    #pragma unroll
    for (int s = 0; s < 8; ++s) {               // FULL unroll: d2s static
        const int b = s & 1;
        float4 p0, p1;
        if (s < 7) {                            // issue prefetch loads early
            p0 = *reinterpret_cast<const float4*>(
                s_emb + (size_t)(sc * CHUNK + (s + 1) * 64 + (tid >> 4)) * D_E + (tid & 15) * 4);
            p1 = *reinterpret_cast<const float4*>(
                s_emb + (size_t)(sc * CHUNK + (s + 1) * 64 + ((512 + tid) >> 4)) * D_E + (tid & 15) * 4);
        }
        const float* tr = &tile[b][lane * 68];
        float a = 0.0f;
        #pragma unroll
        for (int c = 0; c < 16; ++c) {
            float4 sv = *reinterpret_cast<const float4*>(tr + c * 4);
            a = fmaf(q0[c * 4 + 0], sv.x, a);
            a = fmaf(q0[c * 4 + 1], sv.y, a);
            a = fmaf(q0[c * 4 + 2], sv.z, a);
            a = fmaf(q0[c * 4 + 3], sv.w, a);
        }
        const int grow = sc * CHUNK + s * 64 + lane;
        float d2 = fmaxf(qn + s_norm[grow] - 2.0f * a, 0.0f);
        if (d2 < 1e-3f) {
            // possible isclose duplicate (true mask needs d2 <= 2.6e-8; fp32
            // error <= ~1e-5 -> 100x margin, ~never taken); q from global.
            bool close = true;
            for (int k = 0; k < D_E; ++k) {
                float svk = tr[k];
                close = close && (fabsf(q0[k] - svk) <= (ATOLC + RTOLC * fabsf(svk)));
            }
            if (close) d2 = INFINITY;
        }
        d2s[s] = d2;
        if (s < 7) {                            // write prefetch after compute
            *reinterpret_cast<float4*>(&tile[b ^ 1][(tid >> 4) * 68 + (tid & 15) * 4]) = p0;
            *reinterpret_cast<float4*>(&tile[b ^ 1][((512 + tid) >> 4) * 68 + (tid & 15) * 4]) = p1;
        }
        __syncthreads();
    }

    // ---- keys: (d2bits << 9) | local_row, local_row = s*64+lane in [0,512)
    ull sk[8];
    #pragma unroll
    for (int j = 0; j < 8; ++j)
        sk[j] = ((ull)__float_as_uint(d2s[j]) << 9) | (unsigned)(j * 64 + lane);

    // bitonic sort 8 ascending (static indices)
    #pragma unroll
    for (int k = 2; k <= 8; k <<= 1) {
        #pragma unroll
        for (int j = k >> 1; j > 0; j >>= 1) {
            #pragma unroll
            for (int i = 0; i < 8; ++i) {
                int ixj = i ^ j;
                if (ixj > i) {
                    ull a_ = sk[i], b_ = sk[ixj];
                    bool up = (i & k) == 0;
                    bool c_ = up ? (b_ < a_) : (a_ < b_);
                    sk[i] = c_ ? b_ : a_; sk[ixj] = c_ ? a_ : b_;
                }
            }
        }
    }

    // 32 rounds: u32 d2-min + ballot winner (rare exact row tie-break)
    ull lkey = sk[0];
    for (int it = 0; it < KSEL; ++it) {
        unsigned lv = (unsigned)(lkey >> 9);
        unsigned m = lv;
        #pragma unroll
        for (int off = 1; off < 64; off <<= 1) {
            unsigned o = __shfl_xor(m, off);
            m = o < m ? o : m;
        }
        ull tb = __ballot(lv == m);
        if (__popcll(tb) > 1) {
            unsigned rr = (lv == m) ? (unsigned)(lkey & 511u) : 0xffffffffu;
            unsigned rm = rr;
            #pragma unroll
            for (int off = 1; off < 64; off <<= 1) {
                unsigned o = __shfl_xor(rm, off);
                rm = o < rm ? o : rm;
            }
            tb = __ballot(rr == rm);
        }
        const int wl = (int)(__ffsll((long long)tb) - 1);
        if (lane == wl) {
            win_l[wid][it] = lkey;
            #pragma unroll
            for (int j = 0; j < 7; ++j) sk[j] = sk[j + 1];
            sk[7] = ~0ull;
            lkey = sk[0];
        }
    }

    // parallel label fetch + emit (sorted by (d2, idx)); same-wave LDS reads
    if (lane < KSEL) {
        ull m = win_l[wid][lane];
        unsigned gidx = (unsigned)(sc * CHUNK) + (unsigned)(m & 511u);
        float lab = labels[gidx];
        ull* dst = cand + ((size_t)qiu * NCH + sc) * KSEL;
        dst[lane] = ((ull)(unsigned)(m >> 9) << 32) | (ull)__float_as_uint(lab);
    }
}

// ---------------------------------------------------------------------------
// Phase B: wave per query; lanes 0..31 merge the 32 sorted chunk lists;
// labels ride in the candidate payload.
__global__ __launch_bounds__(256) void knn_phaseB(
    const ull* __restrict__ cand, float* __restrict__ out)
{
    const int lane = threadIdx.x & 63;
    const int wid  = threadIdx.x >> 6;
    const int q    = blockIdx.x * 4 + wid;

    const bool act = lane < NCH;
    const ull* lst = cand + ((size_t)q * NCH + (lane & 31)) * KSEL;
    int ptr = 0;
    ull cur = act ? lst[0] : ~0ull;

    float d0 = 0.0f, sw = 0.0f, sl = 0.0f;
    for (int it = 0; it < KSEL; ++it) {
        unsigned mv = (unsigned)(cur >> 32);
        unsigned ml = (unsigned)cur;
        #pragma unroll
        for (int off = 1; off < 32; off <<= 1) {    // min over lanes 0..31
            unsigned ov = __shfl_xor(mv, off);
            unsigned ol = __shfl_xor(ml, off);
            bool take = (ov < mv) || (ov == mv && (lane & off));
            mv = take ? ov : mv;
            ml = take ? ol : ml;
        }
        ull bl = __ballot(act && (unsigned)(cur >> 32) == mv);
        int wl = (int)(__ffsll((long long)bl) - 1);
        if (lane == wl) {
            ++ptr;
            cur = (ptr < KSEL) ? lst[ptr] : ~0ull;
        }
        if (lane == 0) {
            float d = sqrtf(__uint_as_float(mv));
            if (it == 0) d0 = d;
            float w = expf((d0 - d) * INV_T);
            sw += w;
            sl += w * __uint_as_float(ml);
        }
    }
    if (lane == 0) out[q] = sl / sw;
}

// ---------------------------------------------------------------------------
extern "C" void kernel_launch(void* const* d_in, const int* in_sizes, int n_in,
                              void* d_out, int out_size, void* d_ws, size_t ws_size,
                              hipStream_t stream) {
    const float* x      = (const float*)d_in[0];   // [256,256]
    const float* sx     = (const float*)d_in[1];   // [16384,256]
    const float* labels = (const float*)d_in[2];   // [16384,1]
    const float* W1     = (const float*)d_in[3];   // [64,256]
    const float* b1     = (const float*)d_in[4];
    const float* W2     = (const float*)d_in[5];   // [64,64]
    const float* b2     = (const float*)d_in[6];
    const float* W3     = (const float*)d_in[7];   // [64,64]
    const float* b3     = (const float*)d_in[8];
    float* out = (float*)d_out;

    float* ws     = (float*)d_ws;
    float* s_emb  = ws;                              // 16384*64
    float* s_norm = s_emb + (size_t)N_SUP * D_E;     // 16384
    float* q_emb  = s_norm + N_SUP;                  // 256*64
    float* q_norm = q_emb + (size_t)NQ * D_E;        // 256
    ull*   cand   = (ull*)(q_norm + NQ);             // 256*32*32 ull = 2 MB
    float4* W1P   = (float4*)(cand + (size_t)NQ * NCH * KSEL);  // 4096 float4
    float4* W2P   = W1P + 64 * 64;                   // 1024
    float4* W3P   = W2P + 16 * 64;                   // 1024

    prep_w<<<16, 256, 0, stream>>>(W1, W2, W3, W1P, W2P, W3P);
    embed_kernel<<<(N_SUP + NQ) / 32, 256, 0, stream>>>(
        sx, x, W1P, b1, W2P, b2, W3P, b3, s_emb, s_norm, q_emb, q_norm);
    knn_phaseA<<<NQG * NCH, 512, 0, stream>>>(s_emb, s_norm, q_emb, q_norm,
                                              labels, cand);
    knn_phaseB<<<NQ / 4, 256, 0, stream>>>(cand, out);
}

// Round 11
// 101.293 us; speedup vs baseline: 2.2533x; 2.2533x over previous
//
#include <hip/hip_runtime.h>
#include <math.h>

#define D_IN   256
#define D_E    64
#define N_SUP  16384
#define NQ     256
#define KSEL   32
#define RTOLC  1e-5f
#define ATOLC  1e-5f
#define INV_T  10.0f    // 1/TEMPERATURE

#define CHUNK  1024     // support rows per phase-A block
#define NCH    16       // support chunks
#define QG     16       // queries per phase-A block (2 per wave)
#define NQG    16       // query groups

typedef unsigned long long ull;

__device__ __forceinline__ float gelu_exact(float x) {
    return 0.5f * x * (1.0f + erff(x * 0.70710678118654752440f));
}

// ---------------------------------------------------------------------------
// Embed: 260 blocks x 256 threads. Block = 64 rows. Thread = 4 rows x 4 feats
// register tile: per k, 1 ds_read_b128 (x, transposed chunk) + 1 ds_read_b128
// (w, transposed chunk) feeds 16 FMA. x and W double-buffered in LDS (74 KB,
// 2 blocks/CU). FMA chain per (row,f) is k-ascending -> same numerics as ever.
__global__ __launch_bounds__(256, 2) void embed_kernel(
    const float* __restrict__ sx, const float* __restrict__ x,
    const float* __restrict__ W1, const float* __restrict__ b1,
    const float* __restrict__ W2, const float* __restrict__ b2,
    const float* __restrict__ W3, const float* __restrict__ b3,
    float* __restrict__ s_emb, float* __restrict__ s_norm,
    float* __restrict__ q_emb, float* __restrict__ q_norm)
{
    __shared__ float xc[2][64][68];   // x chunk [k][row]; xc[0] later hA, xc[1] hB
    __shared__ float wc[2][64][68];   // W chunk [k][f];   wc[0] later W2T, wc[1] W3T
    __shared__ float nsq[64][17];

    const int tid = threadIdx.x;
    const int rg  = tid >> 4;         // row group (4 rows)
    const int fg  = tid & 15;         // feature group (4 feats)
    const bool isq = blockIdx.x >= (N_SUP / 64);
    const int rowbase = isq ? (int)(blockIdx.x - N_SUP / 64) * 64
                            : (int)blockIdx.x * 64;
    const float* src = (isq ? x : sx) + (size_t)rowbase * D_IN;

    // stage x chunk kc (transposed) into xc[b]
    #define STAGE_X(kc_, b_)                                                   \
        {                                                                      \
            _Pragma("unroll")                                                  \
            for (int i_ = 0; i_ < 4; ++i_) {                                   \
                int g_ = i_ * 256 + tid;                                       \
                int row_ = g_ >> 4, c4_ = g_ & 15;                             \
                float4 v_ = *reinterpret_cast<const float4*>(                  \
                    src + (size_t)row_ * D_IN + (kc_) * 64 + c4_ * 4);         \
                xc[b_][c4_ * 4 + 0][row_] = v_.x;                              \
                xc[b_][c4_ * 4 + 1][row_] = v_.y;                              \
                xc[b_][c4_ * 4 + 2][row_] = v_.z;                              \
                xc[b_][c4_ * 4 + 3][row_] = v_.w;                              \
            }                                                                  \
        }
    // stage W1 chunk kc (transposed) into wc[b]
    #define STAGE_W1(kc_, b_)                                                  \
        {                                                                      \
            _Pragma("unroll")                                                  \
            for (int i_ = 0; i_ < 4; ++i_) {                                   \
                int g_ = i_ * 256 + tid;                                       \
                int f_ = g_ >> 4, c4_ = g_ & 15;                               \
                float4 w_ = *reinterpret_cast<const float4*>(                  \
                    W1 + (size_t)f_ * D_IN + (kc_) * 64 + c4_ * 4);            \
                wc[b_][c4_ * 4 + 0][f_] = w_.x;                                \
                wc[b_][c4_ * 4 + 1][f_] = w_.y;                                \
                wc[b_][c4_ * 4 + 2][f_] = w_.z;                                \
                wc[b_][c4_ * 4 + 3][f_] = w_.w;                                \
            }                                                                  \
        }
    // 64x64 square weight (transposed) into wc[b]
    #define STAGE_WSQ(Wp_, b_)                                                 \
        {                                                                      \
            _Pragma("unroll")                                                  \
            for (int i_ = 0; i_ < 4; ++i_) {                                   \
                int g_ = i_ * 256 + tid;                                       \
                int f_ = g_ >> 4, c4_ = g_ & 15;                               \
                float4 w_ = *reinterpret_cast<const float4*>(                  \
                    (Wp_) + (size_t)f_ * D_E + c4_ * 4);                       \
                wc[b_][c4_ * 4 + 0][f_] = w_.x;                                \
                wc[b_][c4_ * 4 + 1][f_] = w_.y;                                \
                wc[b_][c4_ * 4 + 2][f_] = w_.z;                                \
                wc[b_][c4_ * 4 + 3][f_] = w_.w;                                \
            }                                                                  \
        }
    // one 64-k GEMM pass: acc[j][i] += w[k][fg*4+i] * x[k][rg*4+j]
    #define GEMM64(XB_, WB_, ACC_)                                             \
        {                                                                      \
            _Pragma("unroll 8")                                                \
            for (int k_ = 0; k_ < 64; ++k_) {                                  \
                float4 xv_ = *reinterpret_cast<const float4*>(&XB_[k_][rg * 4]); \
                float4 wv_ = *reinterpret_cast<const float4*>(&WB_[k_][fg * 4]); \
                ACC_[0][0] = fmaf(wv_.x, xv_.x, ACC_[0][0]);                   \
                ACC_[0][1] = fmaf(wv_.y, xv_.x, ACC_[0][1]);                   \
                ACC_[0][2] = fmaf(wv_.z, xv_.x, ACC_[0][2]);                   \
                ACC_[0][3] = fmaf(wv_.w, xv_.x, ACC_[0][3]);                   \
                ACC_[1][0] = fmaf(wv_.x, xv_.y, ACC_[1][0]);                   \
                ACC_[1][1] = fmaf(wv_.y, xv_.y, ACC_[1][1]);                   \
                ACC_[1][2] = fmaf(wv_.z, xv_.y, ACC_[1][2]);                   \
                ACC_[1][3] = fmaf(wv_.w, xv_.y, ACC_[1][3]);                   \
                ACC_[2][0] = fmaf(wv_.x, xv_.z, ACC_[2][0]);                   \
                ACC_[2][1] = fmaf(wv_.y, xv_.z, ACC_[2][1]);                   \
                ACC_[2][2] = fmaf(wv_.z, xv_.z, ACC_[2][2]);                   \
                ACC_[2][3] = fmaf(wv_.w, xv_.z, ACC_[2][3]);                   \
                ACC_[3][0] = fmaf(wv_.x, xv_.w, ACC_[3][0]);                   \
                ACC_[3][1] = fmaf(wv_.y, xv_.w, ACC_[3][1]);                   \
                ACC_[3][2] = fmaf(wv_.z, xv_.w, ACC_[3][2]);                   \
                ACC_[3][3] = fmaf(wv_.w, xv_.w, ACC_[3][3]);                   \
            }                                                                  \
        }

    // ---- layer 1: K=256 in 4 chunks, double-buffered
    float4 bv1 = *reinterpret_cast<const float4*>(b1 + fg * 4);
    float acc[4][4];
    #pragma unroll
    for (int j = 0; j < 4; ++j) {
        acc[j][0] = bv1.x; acc[j][1] = bv1.y; acc[j][2] = bv1.z; acc[j][3] = bv1.w;
    }
    STAGE_X(0, 0); STAGE_W1(0, 0);
    __syncthreads();
    #pragma unroll
    for (int kc = 0; kc < 4; ++kc) {
        const int b = kc & 1;
        if (kc < 3) { STAGE_X(kc + 1, b ^ 1); STAGE_W1(kc + 1, b ^ 1); }
        GEMM64(xc[b], wc[b], acc);
        __syncthreads();
    }

    // hA (gelu) -> xc[0] transposed [f][row]; stage W2 -> wc[0], W3 -> wc[1]
    #pragma unroll
    for (int j = 0; j < 4; ++j)
        #pragma unroll
        for (int i = 0; i < 4; ++i)
            xc[0][fg * 4 + i][rg * 4 + j] = gelu_exact(acc[j][i]);
    STAGE_WSQ(W2, 0);
    STAGE_WSQ(W3, 1);
    __syncthreads();

    // ---- layer 2: hA (xc[0]) x W2T (wc[0]) -> hB (xc[1])
    float4 bv2 = *reinterpret_cast<const float4*>(b2 + fg * 4);
    float a2[4][4];
    #pragma unroll
    for (int j = 0; j < 4; ++j) {
        a2[j][0] = bv2.x; a2[j][1] = bv2.y; a2[j][2] = bv2.z; a2[j][3] = bv2.w;
    }
    GEMM64(xc[0], wc[0], a2);
    __syncthreads();
    #pragma unroll
    for (int j = 0; j < 4; ++j)
        #pragma unroll
        for (int i = 0; i < 4; ++i)
            xc[1][fg * 4 + i][rg * 4 + j] = gelu_exact(a2[j][i]);
    __syncthreads();

    // ---- layer 3: hB (xc[1]) x W3T (wc[1]) -> sigmoid + norm
    float4 bv3 = *reinterpret_cast<const float4*>(b3 + fg * 4);
    float a3[4][4];
    #pragma unroll
    for (int j = 0; j < 4; ++j) {
        a3[j][0] = bv3.x; a3[j][1] = bv3.y; a3[j][2] = bv3.z; a3[j][3] = bv3.w;
    }
    GEMM64(xc[1], wc[1], a3);

    float* E   = isq ? q_emb  : s_emb;
    float* Nrm = isq ? q_norm : s_norm;
    #pragma unroll
    for (int j = 0; j < 4; ++j) {
        float e0 = 1.0f / (1.0f + expf(-a3[j][0]));
        float e1 = 1.0f / (1.0f + expf(-a3[j][1]));
        float e2 = 1.0f / (1.0f + expf(-a3[j][2]));
        float e3 = 1.0f / (1.0f + expf(-a3[j][3]));
        *reinterpret_cast<float4*>(E + (size_t)(rowbase + rg * 4 + j) * D_E + fg * 4)
            = make_float4(e0, e1, e2, e3);
        a3[j][0] = fmaf(e0, e0, fmaf(e1, e1, fmaf(e2, e2, e3 * e3)));
    }
    __syncthreads();                  // xc/wc reads done (reuse nsq region safely)
    #pragma unroll
    for (int j = 0; j < 4; ++j) nsq[rg * 4 + j][fg] = a3[j][0];
    __syncthreads();
    if (tid < 64) {
        float s = 0.0f;
        #pragma unroll
        for (int g = 0; g < 16; ++g) s += nsq[tid][g];
        Nrm[rowbase + tid] = s;
    }
    #undef STAGE_X
    #undef STAGE_W1
    #undef STAGE_WSQ
    #undef GEMM64
}

// ---------------------------------------------------------------------------
// Phase A: grid 256 (qg = b>>4, sc = b&15), 512 threads, wave = 2 queries
// (both q pointers wave-uniform -> SGPR fma operands; 16 b128 tile reads feed
// 128 FMAs). Tile double-buffered, 1 barrier/stage (R10 scheme). d2 in
// registers, fully static. Selection per query: sort-16 + 32 rounds of
// u32-min + ballot (R10 scheme, absmax-0-verified).
__global__ __launch_bounds__(512, 1) void knn_phaseA(
    const float* __restrict__ s_emb, const float* __restrict__ s_norm,
    const float* __restrict__ q_emb, const float* __restrict__ q_norm,
    const float* __restrict__ labels, ull* __restrict__ cand)
{
    __shared__ float tile[2][64 * 68];          // 34.8 KB
    __shared__ ull   win_l[QG][KSEL];           // 4 KB

    const int tid  = threadIdx.x;
    const int lane = tid & 63;
    const int wid  = tid >> 6;
    const int qg   = blockIdx.x >> 4;
    const int sc   = blockIdx.x & 15;
    const int qiu  = __builtin_amdgcn_readfirstlane(qg * QG + 2 * wid);
    const float* q0 = q_emb + (size_t)qiu * D_E;        // uniform -> s_load
    const float* q1 = q0 + D_E;
    const float  qn0 = q_norm[qiu];
    const float  qn1 = q_norm[qiu + 1];

    #pragma unroll
    for (int i = 0; i < 2; ++i) {               // stage 0
        int g = i * 512 + tid;
        int row = g >> 4, c4 = g & 15;
        float4 v = *reinterpret_cast<const float4*>(
            s_emb + (size_t)(sc * CHUNK + row) * D_E + c4 * 4);
        *reinterpret_cast<float4*>(&tile[0][row * 68 + c4 * 4]) = v;
    }
    __syncthreads();

    float d2a[16], d2b[16];
    #pragma unroll
    for (int s = 0; s < 16; ++s) {              // FULL unroll: static d2 indices
        const int b = s & 1;
        float4 p0, p1;
        if (s < 15) {                           // issue prefetch loads early
            p0 = *reinterpret_cast<const float4*>(
                s_emb + (size_t)(sc * CHUNK + (s + 1) * 64 + (tid >> 4)) * D_E + (tid & 15) * 4);
            p1 = *reinterpret_cast<const float4*>(
                s_emb + (size_t)(sc * CHUNK + (s + 1) * 64 + ((512 + tid) >> 4)) * D_E + (tid & 15) * 4);
        }
        const float* tr = &tile[b][lane * 68];
        float a0 = 0.0f, a1 = 0.0f;
        #pragma unroll
        for (int c = 0; c < 16; ++c) {
            float4 sv = *reinterpret_cast<const float4*>(tr + c * 4);
            a0 = fmaf(q0[c * 4 + 0], sv.x, a0);
            a0 = fmaf(q0[c * 4 + 1], sv.y, a0);
            a0 = fmaf(q0[c * 4 + 2], sv.z, a0);
            a0 = fmaf(q0[c * 4 + 3], sv.w, a0);
            a1 = fmaf(q1[c * 4 + 0], sv.x, a1);
            a1 = fmaf(q1[c * 4 + 1], sv.y, a1);
            a1 = fmaf(q1[c * 4 + 2], sv.z, a1);
            a1 = fmaf(q1[c * 4 + 3], sv.w, a1);
        }
        const int grow = sc * CHUNK + s * 64 + lane;
        const float sn = s_norm[grow];
        float d20 = fmaxf(qn0 + sn - 2.0f * a0, 0.0f);
        float d21 = fmaxf(qn1 + sn - 2.0f * a1, 0.0f);
        if (d20 < 1e-3f) {
            // possible isclose duplicate (true mask needs d2 <= 2.6e-8; fp32
            // error <= ~1e-5 -> 100x margin, ~never taken); q via s_load.
            bool close = true;
            for (int k = 0; k < D_E; ++k) {
                float svk = tr[k];
                close = close && (fabsf(q0[k] - svk) <= (ATOLC + RTOLC * fabsf(svk)));
            }
            if (close) d20 = INFINITY;
        }
        if (d21 < 1e-3f) {
            bool close = true;
            for (int k = 0; k < D_E; ++k) {
                float svk = tr[k];
                close = close && (fabsf(q1[k] - svk) <= (ATOLC + RTOLC * fabsf(svk)));
            }
            if (close) d21 = INFINITY;
        }
        d2a[s] = d20;
        d2b[s] = d21;
        if (s < 15) {                           // write prefetch after compute
            *reinterpret_cast<float4*>(&tile[b ^ 1][(tid >> 4) * 68 + (tid & 15) * 4]) = p0;
            *reinterpret_cast<float4*>(&tile[b ^ 1][((512 + tid) >> 4) * 68 + (tid & 15) * 4]) = p1;
        }
        __syncthreads();
    }

    // ---- selection for the wave's two queries, sequentially
    #pragma unroll
    for (int h = 0; h < 2; ++h) {
        ull sk[16];
        #pragma unroll
        for (int j = 0; j < 16; ++j) {
            float d2 = h ? d2b[j] : d2a[j];
            sk[j] = ((ull)__float_as_uint(d2) << 10) | (unsigned)(j * 64 + lane);
        }
        // bitonic sort 16 ascending (static indices)
        #pragma unroll
        for (int k = 2; k <= 16; k <<= 1) {
            #pragma unroll
            for (int j = k >> 1; j > 0; j >>= 1) {
                #pragma unroll
                for (int i = 0; i < 16; ++i) {
                    int ixj = i ^ j;
                    if (ixj > i) {
                        ull a_ = sk[i], b_ = sk[ixj];
                        bool up = (i & k) == 0;
                        bool c_ = up ? (b_ < a_) : (a_ < b_);
                        sk[i] = c_ ? b_ : a_; sk[ixj] = c_ ? a_ : b_;
                    }
                }
            }
        }
        // 32 rounds: u32 d2-min + ballot winner (rare exact row tie-break)
        ull lkey = sk[0];
        for (int it = 0; it < KSEL; ++it) {
            unsigned lv = (unsigned)(lkey >> 10);
            unsigned m = lv;
            #pragma unroll
            for (int off = 1; off < 64; off <<= 1) {
                unsigned o = __shfl_xor(m, off);
                m = o < m ? o : m;
            }
            ull tb = __ballot(lv == m);
            if (__popcll(tb) > 1) {
                unsigned rr = (lv == m) ? (unsigned)(lkey & 1023u) : 0xffffffffu;
                unsigned rm = rr;
                #pragma unroll
                for (int off = 1; off < 64; off <<= 1) {
                    unsigned o = __shfl_xor(rm, off);
                    rm = o < rm ? o : rm;
                }
                tb = __ballot(rr == rm);
            }
            const int wl = (int)(__ffsll((long long)tb) - 1);
            if (lane == wl) {
                win_l[2 * wid + h][it] = lkey;
                #pragma unroll
                for (int j = 0; j < 15; ++j) sk[j] = sk[j + 1];
                sk[15] = ~0ull;
                lkey = sk[0];
            }
        }
    }

    // parallel label fetch + emit: lanes 0..31 -> query 0, 32..63 -> query 1
    {
        const int h = lane >> 5;
        const int e = lane & 31;
        ull m = win_l[2 * wid + h][e];
        unsigned gidx = (unsigned)(sc * CHUNK) + (unsigned)(m & 1023u);
        float lab = labels[gidx];
        ull* dst = cand + ((size_t)(qiu + h) * NCH + sc) * KSEL;
        dst[e] = ((ull)(unsigned)(m >> 10) << 32) | (ull)__float_as_uint(lab);
    }
}

// ---------------------------------------------------------------------------
// Phase B: wave per query; lanes 0..15 merge the 16 sorted chunk lists
// (d2-bit compare, lower-lane tie-break = lower chunk = lower global index);
// labels ride in the candidate payload.
__global__ __launch_bounds__(256) void knn_phaseB(
    const ull* __restrict__ cand, float* __restrict__ out)
{
    const int lane = threadIdx.x & 63;
    const int wid  = threadIdx.x >> 6;
    const int q    = blockIdx.x * 4 + wid;

    const bool act = lane < NCH;
    const ull* lst = cand + ((size_t)q * NCH + (lane & 15)) * KSEL;
    int ptr = 0;
    ull cur = act ? lst[0] : ~0ull;

    float d0 = 0.0f, sw = 0.0f, sl = 0.0f;
    for (int it = 0; it < KSEL; ++it) {
        unsigned mv = (unsigned)(cur >> 32);
        unsigned ml = (unsigned)cur;
        #pragma unroll
        for (int off = 1; off < 16; off <<= 1) {
            unsigned ov = __shfl_xor(mv, off);
            unsigned ol = __shfl_xor(ml, off);
            bool take = (ov < mv) || (ov == mv && (lane & off));
            mv = take ? ov : mv;
            ml = take ? ol : ml;
        }
        ull b = __ballot(act && (unsigned)(cur >> 32) == mv);
        int wl = (int)(__ffsll((long long)b) - 1);
        if (lane == wl) {
            ++ptr;
            cur = (ptr < KSEL) ? lst[ptr] : ~0ull;
        }
        if (lane == 0) {
            float d = sqrtf(__uint_as_float(mv));
            if (it == 0) d0 = d;
            float w = expf((d0 - d) * INV_T);
            sw += w;
            sl += w * __uint_as_float(ml);
        }
    }
    if (lane == 0) out[q] = sl / sw;
}

// ---------------------------------------------------------------------------
extern "C" void kernel_launch(void* const* d_in, const int* in_sizes, int n_in,
                              void* d_out, int out_size, void* d_ws, size_t ws_size,
                              hipStream_t stream) {
    const float* x      = (const float*)d_in[0];   // [256,256]
    const float* sx     = (const float*)d_in[1];   // [16384,256]
    const float* labels = (const float*)d_in[2];   // [16384,1]
    const float* W1     = (const float*)d_in[3];   // [64,256]
    const float* b1     = (const float*)d_in[4];
    const float* W2     = (const float*)d_in[5];   // [64,64]
    const float* b2     = (const float*)d_in[6];
    const float* W3     = (const float*)d_in[7];   // [64,64]
    const float* b3     = (const float*)d_in[8];
    float* out = (float*)d_out;

    float* ws     = (float*)d_ws;
    float* s_emb  = ws;                              // 16384*64
    float* s_norm = s_emb + (size_t)N_SUP * D_E;     // 16384
    float* q_emb  = s_norm + N_SUP;                  // 256*64
    float* q_norm = q_emb + (size_t)NQ * D_E;        // 256
    ull*   cand   = (ull*)(q_norm + NQ);             // 256*16*32 ull = 1 MB

    embed_kernel<<<(N_SUP + NQ) / 64, 256, 0, stream>>>(
        sx, x, W1, b1, W2, b2, W3, b3, s_emb, s_norm, q_emb, q_norm);
    knn_phaseA<<<NQG * NCH, 512, 0, stream>>>(s_emb, s_norm, q_emb, q_norm,
                                              labels, cand);
    knn_phaseB<<<NQ / 4, 256, 0, stream>>>(cand, out);
}